// Round 1
// 294.720 us; speedup vs baseline: 1.5964x; 1.5964x over previous
//
#include <hip/hip_runtime.h>
#include <hip/hip_bf16.h>
#include <math.h>

// PhiMoE sparse MoE block. E=8, H=1024, F=2048, T=1024.
// Inputs  (float32): hidden_states [1,1024,1024], gate_w [8,1024],
//   w1 [8,2048,1024], w2 [8,1024,2048], w3 [8,2048,1024]
// Outputs (float32, concat): final [1,1024,1024], router_logits [1024,8]
// Top-2 routing -> gather per expert; pipelined LDS-dbuf grouped GEMMs.
// R1: flattened dense m-tile grids (device-side prefix over cnt[]) to kill
// XCD partition camping — old grid put all working blocks on XCDs 0-1
// (gemm1) / 0-3 (gemm2) since working blockIdx.x aliased id%8.

#define T_TOK 1024
#define H_DIM 1024
#define F_DIM 2048
#define N_EXP 8
#define JIT 0.01f

#define BK  64
#define LDK 72   // LDS row stride (bf16 elems): conflict-free for b64 writes + b128 reads

// flat m-tile upper bounds: sum_e ceil(cnt_e/TILE) < 2048/TILE + 8
#define MT1_MAX 24   // 128-row tiles
#define MT2_MAX 40   // 64-row tiles

typedef __bf16 bf16_t;
typedef __bf16 bf16x8 __attribute__((ext_vector_type(8)));
typedef __bf16 bf16x4 __attribute__((ext_vector_type(4)));
typedef float f32x4 __attribute__((ext_vector_type(4)));

__device__ inline bf16x4 cvt4(float4 v) {
    bf16x4 r;
    r[0] = (bf16_t)v.x; r[1] = (bf16_t)v.y; r[2] = (bf16_t)v.z; r[3] = (bf16_t)v.w;
    return r;
}

// workspace layout (bytes)
#define WS_CNT   0
#define WS_BASE  64
#define WS_TOK   128
#define WS_WGT   (128 + 32768)
#define WS_SLOT  (WS_WGT + 32768)
#define WS_INTER 131072              // bf16 [2048][2048] compacted intermediate (8 MB)
#define WS_ACC   (131072 + 8388608)  // f32  [2][1024][1024] slot accumulators (8 MB)

// ---------------- Router: logits + sparsemixer top-2 ----------------
__global__ __launch_bounds__(256) void router_k(
    const float* __restrict__ x, const float* __restrict__ gw,
    float* __restrict__ logits_out,
    int* __restrict__ cnt, int* __restrict__ tok,
    float* __restrict__ wgt, int* __restrict__ slot)
{
    int t = blockIdx.x;
    int tid = threadIdx.x;
    __shared__ float sm[N_EXP][256];

    float acc[N_EXP];
#pragma unroll
    for (int e = 0; e < N_EXP; e++) acc[e] = 0.f;
#pragma unroll
    for (int j = 0; j < H_DIM / 256; j++) {
        int h = tid + j * 256;
        float xv = x[t * H_DIM + h];
#pragma unroll
        for (int e = 0; e < N_EXP; e++) acc[e] += xv * gw[e * H_DIM + h];
    }
#pragma unroll
    for (int e = 0; e < N_EXP; e++) sm[e][tid] = acc[e];
    __syncthreads();
    for (int s = 128; s > 0; s >>= 1) {
        if (tid < s) {
#pragma unroll
            for (int e = 0; e < N_EXP; e++) sm[e][tid] += sm[e][tid + s];
        }
        __syncthreads();
    }
    if (tid == 0) {
        float s[N_EXP];
#pragma unroll
        for (int e = 0; e < N_EXP; e++) {
            s[e] = sm[e][0];
            logits_out[t * N_EXP + e] = s[e];
        }
        float max1 = -INFINITY; int sel1 = 0;
        for (int e = 0; e < N_EXP; e++) if (s[e] > max1) { max1 = s[e]; sel1 = e; }
        float denom1 = 0.f;
        for (int e = 0; e < N_EXP; e++) {
            float factor = fmaxf(fabsf(s[e]), max1);
            bool m = ((max1 - s[e]) / factor) > (2.0f * JIT);
            if (!m) denom1 += expf(s[e] - max1);
        }
        float mult1 = 1.0f / denom1;
        float max2 = -INFINITY; int sel2 = 0;
        for (int e = 0; e < N_EXP; e++)
            if (e != sel1 && s[e] > max2) { max2 = s[e]; sel2 = e; }
        float denom2 = 0.f;
        for (int e = 0; e < N_EXP; e++) {
            if (e == sel1) continue;
            float factor = fmaxf(fabsf(s[e]), max2);
            bool m = ((max2 - s[e]) / factor) > (2.0f * JIT);
            if (!m) denom2 += expf(s[e] - max2);
        }
        float mult2 = 1.0f / denom2;

        int p1 = atomicAdd(&cnt[sel1], 1);
        tok[sel1 * T_TOK + p1] = t; wgt[sel1 * T_TOK + p1] = mult1; slot[sel1 * T_TOK + p1] = 0;
        int p2 = atomicAdd(&cnt[sel2], 1);
        tok[sel2 * T_TOK + p2] = t; wgt[sel2 * T_TOK + p2] = mult2; slot[sel2 * T_TOK + p2] = 1;
    }
}

__global__ void prefix_k(const int* __restrict__ cnt, int* __restrict__ base)
{
    if (threadIdx.x == 0 && blockIdx.x == 0) {
        int a = 0;
        for (int e = 0; e < N_EXP; e++) { base[e] = a; a += cnt[e]; }
    }
}

// ---------------- GEMM1: inter = silu(x@w1^T) * (x@w3^T) ----------------
// 128x64 tile, BK=64, LDS double-buffer + reg prefetch, one barrier per iter.
// grid (MT1_MAX*32) 1D, block 256. Flat m-tile -> (expert, m0) via prefix of cnt.
// id = mt*32 + nt: same-nt (same weight tile) blocks are stride-32 apart ->
// same XCD under id%8 round-robin -> weight tiles stay L2-local.
__global__ __launch_bounds__(256) void gemm1_k(
    const float* __restrict__ x,
    const float* __restrict__ w1,
    const float* __restrict__ w3,
    const int* __restrict__ cnt, const int* __restrict__ base,
    const int* __restrict__ tok,
    bf16_t* __restrict__ inter)
{
    int mt = blockIdx.x >> 5;       // flat m-tile across experts
    int nt = blockIdx.x & 31;       // 32 n-tiles of 64
    int e = 0, m0 = 0, found = 0, accb = 0;
#pragma unroll
    for (int ee = 0; ee < N_EXP; ee++) {
        int b = (cnt[ee] + 127) >> 7;
        if (!found && mt < accb + b) { e = ee; m0 = (mt - accb) << 7; found = 1; }
        accb += b;
    }
    if (!found) return;
    int cntE = cnt[e];
    int n0 = nt * 64;
    int tid = threadIdx.x;
    int lane = tid & 63, quad = lane >> 4, l16 = lane & 15;
    int wave = tid >> 6;

    __shared__ __align__(16) bf16_t Al[2][128 * LDK];
    __shared__ __align__(16) bf16_t B1l[2][64 * LDK];
    __shared__ __align__(16) bf16_t B3l[2][64 * LDK];
    __shared__ int tokL[128];

    if (tid < 128) {
        int r = m0 + tid;
        tokL[tid] = tok[e * T_TOK + (r < cntE ? r : cntE - 1)];
    }
    __syncthreads();

    // staging coords: A 128x64 f32 = 2048 float4 chunks (8/thread); B 64x64 = 1024 (4/thread)
    int rA[8], kA[8];
    const float* aP[8];
#pragma unroll
    for (int i = 0; i < 8; i++) {
        int c = tid + i * 256;
        rA[i] = c >> 4; kA[i] = c & 15;
        aP[i] = x + (size_t)tokL[rA[i]] * H_DIM + kA[i] * 4;
    }
    int rB[4], kB[4];
    const float* b1P[4];
    const float* b3P[4];
    const float* w1e = w1 + (size_t)e * F_DIM * H_DIM + (size_t)n0 * H_DIM;
    const float* w3e = w3 + (size_t)e * F_DIM * H_DIM + (size_t)n0 * H_DIM;
#pragma unroll
    for (int i = 0; i < 4; i++) {
        int c = tid + i * 256;
        rB[i] = c >> 4; kB[i] = c & 15;
        b1P[i] = w1e + (size_t)rB[i] * H_DIM + kB[i] * 4;
        b3P[i] = w3e + (size_t)rB[i] * H_DIM + kB[i] * 4;
    }

    f32x4 acc1[2][4], acc3[2][4];
#pragma unroll
    for (int i = 0; i < 2; i++)
#pragma unroll
        for (int j = 0; j < 4; j++) {
            acc1[i][j] = f32x4{0.f, 0.f, 0.f, 0.f};
            acc3[i][j] = f32x4{0.f, 0.f, 0.f, 0.f};
        }

    float4 pA[8], p1[4], p3[4];
#pragma unroll
    for (int i = 0; i < 8; i++) pA[i] = *(const float4*)(aP[i]);
#pragma unroll
    for (int i = 0; i < 4; i++) { p1[i] = *(const float4*)(b1P[i]); p3[i] = *(const float4*)(b3P[i]); }

    for (int kk = 0; kk < H_DIM / BK; kk++) {
        int buf = kk & 1;
        // stage prefetched regs into LDS (vmcnt wait lands here, one iter after issue)
#pragma unroll
        for (int i = 0; i < 8; i++)
            *(bf16x4*)&Al[buf][rA[i] * LDK + kA[i] * 4] = cvt4(pA[i]);
#pragma unroll
        for (int i = 0; i < 4; i++) {
            *(bf16x4*)&B1l[buf][rB[i] * LDK + kB[i] * 4] = cvt4(p1[i]);
            *(bf16x4*)&B3l[buf][rB[i] * LDK + kB[i] * 4] = cvt4(p3[i]);
        }
        // issue next iter's loads (overlap with MFMA phase below)
        if (kk + 1 < H_DIM / BK) {
            int k0 = (kk + 1) * BK;
#pragma unroll
            for (int i = 0; i < 8; i++) pA[i] = *(const float4*)(aP[i] + k0);
#pragma unroll
            for (int i = 0; i < 4; i++) {
                p1[i] = *(const float4*)(b1P[i] + k0);
                p3[i] = *(const float4*)(b3P[i] + k0);
            }
        }
        __syncthreads();
#pragma unroll
        for (int s = 0; s < 2; s++) {
            int ko = s * 32 + quad * 8;
            bf16x8 af[2], b1f[4], b3f[4];
#pragma unroll
            for (int i = 0; i < 2; i++)
                af[i] = *(const bf16x8*)&Al[buf][(wave * 32 + i * 16 + l16) * LDK + ko];
#pragma unroll
            for (int j = 0; j < 4; j++) {
                b1f[j] = *(const bf16x8*)&B1l[buf][(j * 16 + l16) * LDK + ko];
                b3f[j] = *(const bf16x8*)&B3l[buf][(j * 16 + l16) * LDK + ko];
            }
#pragma unroll
            for (int i = 0; i < 2; i++)
#pragma unroll
                for (int j = 0; j < 4; j++) {
                    acc1[i][j] = __builtin_amdgcn_mfma_f32_16x16x32_bf16(af[i], b1f[j], acc1[i][j], 0, 0, 0);
                    acc3[i][j] = __builtin_amdgcn_mfma_f32_16x16x32_bf16(af[i], b3f[j], acc3[i][j], 0, 0, 0);
                }
        }
    }

    int rowBase = base[e];
#pragma unroll
    for (int i = 0; i < 2; i++) {
#pragma unroll
        for (int j = 0; j < 4; j++) {
            int ff = n0 + j * 16 + l16;
#pragma unroll
            for (int r = 0; r < 4; r++) {
                int mm = m0 + wave * 32 + i * 16 + quad * 4 + r;
                if (mm < cntE) {
                    float h1 = acc1[i][j][r], h3 = acc3[i][j][r];
                    float v = (h1 / (1.f + expf(-h1))) * h3;
                    inter[(size_t)(rowBase + mm) * F_DIM + ff] = (bf16_t)v;
                }
            }
        }
    }
}

// ---------------- GEMM2: out = (inter @ w2^T) * wgt, scatter to slot accumulator ----------------
// 64x64 tile, BK=64, same pipeline. grid (MT2_MAX*16) 1D, block 256.
// Flat m-tile -> (expert, m0). Same-nt blocks stride-16 apart -> same XCD.
__global__ __launch_bounds__(256) void gemm2_k(
    const bf16_t* __restrict__ inter,
    const float* __restrict__ w2,
    const int* __restrict__ cnt, const int* __restrict__ base,
    const int* __restrict__ tok,
    const float* __restrict__ wgt, const int* __restrict__ slot,
    float* __restrict__ accOut)
{
    int mt = blockIdx.x >> 4;       // flat m-tile across experts (64-row tiles)
    int nt = blockIdx.x & 15;       // 16 n-tiles of 64
    int e = 0, m0 = 0, found = 0, accb = 0;
#pragma unroll
    for (int ee = 0; ee < N_EXP; ee++) {
        int b = (cnt[ee] + 63) >> 6;
        if (!found && mt < accb + b) { e = ee; m0 = (mt - accb) << 6; found = 1; }
        accb += b;
    }
    if (!found) return;
    int cntE = cnt[e];
    int n0 = nt * 64;
    int tid = threadIdx.x;
    int lane = tid & 63, quad = lane >> 4, l16 = lane & 15;
    int wave = tid >> 6;
    int rowBase = base[e];

    __shared__ __align__(16) bf16_t Al[2][64 * LDK];
    __shared__ __align__(16) bf16_t Bl[2][64 * LDK];

    // A: 64x64 bf16 = 512 bf16x8 chunks (2/thread); B: 64x64 f32 = 1024 float4 (4/thread)
    int rA[2], kA[2];
    const bf16_t* aP[2];
#pragma unroll
    for (int i = 0; i < 2; i++) {
        int c = tid + i * 256;
        rA[i] = c >> 3; kA[i] = c & 7;
        int row = m0 + rA[i]; if (row >= cntE) row = cntE - 1;
        aP[i] = inter + (size_t)(rowBase + row) * F_DIM + kA[i] * 8;
    }
    int rB[4], kB[4];
    const float* bP[4];
    const float* w2e = w2 + (size_t)e * H_DIM * F_DIM + (size_t)n0 * F_DIM;
#pragma unroll
    for (int i = 0; i < 4; i++) {
        int c = tid + i * 256;
        rB[i] = c >> 4; kB[i] = c & 15;
        bP[i] = w2e + (size_t)rB[i] * F_DIM + kB[i] * 4;
    }

    f32x4 acc[4];
#pragma unroll
    for (int j = 0; j < 4; j++) acc[j] = f32x4{0.f, 0.f, 0.f, 0.f};

    bf16x8 pa[2];
    float4 pb[4];
#pragma unroll
    for (int i = 0; i < 2; i++) pa[i] = *(const bf16x8*)(aP[i]);
#pragma unroll
    for (int i = 0; i < 4; i++) pb[i] = *(const float4*)(bP[i]);

    for (int kk = 0; kk < F_DIM / BK; kk++) {
        int buf = kk & 1;
#pragma unroll
        for (int i = 0; i < 2; i++)
            *(bf16x8*)&Al[buf][rA[i] * LDK + kA[i] * 8] = pa[i];
#pragma unroll
        for (int i = 0; i < 4; i++)
            *(bf16x4*)&Bl[buf][rB[i] * LDK + kB[i] * 4] = cvt4(pb[i]);
        if (kk + 1 < F_DIM / BK) {
            int k0 = (kk + 1) * BK;
#pragma unroll
            for (int i = 0; i < 2; i++) pa[i] = *(const bf16x8*)(aP[i] + k0);
#pragma unroll
            for (int i = 0; i < 4; i++) pb[i] = *(const float4*)(bP[i] + k0);
        }
        __syncthreads();
#pragma unroll
        for (int s = 0; s < 2; s++) {
            int ko = s * 32 + quad * 8;
            bf16x8 af = *(const bf16x8*)&Al[buf][(wave * 16 + l16) * LDK + ko];
            bf16x8 bfr[4];
#pragma unroll
            for (int j = 0; j < 4; j++)
                bfr[j] = *(const bf16x8*)&Bl[buf][(j * 16 + l16) * LDK + ko];
#pragma unroll
            for (int j = 0; j < 4; j++)
                acc[j] = __builtin_amdgcn_mfma_f32_16x16x32_bf16(af, bfr[j], acc[j], 0, 0, 0);
        }
    }

#pragma unroll
    for (int r = 0; r < 4; r++) {
        int mm = m0 + wave * 16 + quad * 4 + r;
        if (mm < cntE) {
            int t = tok[e * T_TOK + mm];
            float wv = wgt[e * T_TOK + mm];
            int sl = slot[e * T_TOK + mm];
            float* dst = accOut + (size_t)sl * T_TOK * H_DIM + (size_t)t * H_DIM;
#pragma unroll
            for (int j = 0; j < 4; j++)
                dst[n0 + j * 16 + l16] = acc[j][r] * wv;
        }
    }
}

// ---------------- combine ----------------
__global__ __launch_bounds__(256) void combine_k(const float* __restrict__ acc,
                                                 float* __restrict__ out)
{
    int i = blockIdx.x * 256 + threadIdx.x;
    const float4* a0 = (const float4*)acc;
    const float4* a1 = (const float4*)(acc + (size_t)T_TOK * H_DIM);
    float4 v0 = a0[i];
    float4 v1 = a1[i];
    float4 r;
    r.x = v0.x + v1.x; r.y = v0.y + v1.y; r.z = v0.z + v1.z; r.w = v0.w + v1.w;
    ((float4*)out)[i] = r;
}

extern "C" void kernel_launch(void* const* d_in, const int* in_sizes, int n_in,
                              void* d_out, int out_size, void* d_ws, size_t ws_size,
                              hipStream_t stream) {
    const float* x  = (const float*)d_in[0];
    const float* gw = (const float*)d_in[1];
    const float* w1 = (const float*)d_in[2];
    const float* w2 = (const float*)d_in[3];
    const float* w3 = (const float*)d_in[4];
    float* out = (float*)d_out;
    float* logits_out = out + (size_t)T_TOK * H_DIM;

    char* ws = (char*)d_ws;
    int*    cnt   = (int*)(ws + WS_CNT);
    int*    basep = (int*)(ws + WS_BASE);
    int*    tok   = (int*)(ws + WS_TOK);
    float*  wgt   = (float*)(ws + WS_WGT);
    int*    slot  = (int*)(ws + WS_SLOT);
    bf16_t* inter = (bf16_t*)(ws + WS_INTER);
    float*  accO  = (float*)(ws + WS_ACC);

    hipMemsetAsync(cnt, 0, 64, stream);
    router_k<<<T_TOK, 256, 0, stream>>>(x, gw, logits_out, cnt, tok, wgt, slot);
    prefix_k<<<1, 64, 0, stream>>>(cnt, basep);
    gemm1_k<<<dim3(MT1_MAX * 32), 256, 0, stream>>>(x, w1, w3, cnt, basep, tok, inter);
    gemm2_k<<<dim3(MT2_MAX * 16), 256, 0, stream>>>(inter, w2, cnt, basep, tok, wgt, slot, accO);
    combine_k<<<(T_TOK * H_DIM / 4) / 256, 256, 0, stream>>>(accO, out);
}